// Round 8
// baseline (218.767 us; speedup 1.0000x reference)
//
#include <hip/hip_runtime.h>

#define T_SEQ 2048
#define NB 2
#define NH 16
#define DK 64
#define DMODEL 1024

typedef __bf16 bf16x8 __attribute__((ext_vector_type(8)));
typedef float f32x4 __attribute__((ext_vector_type(4)));
typedef unsigned short ushortx8 __attribute__((ext_vector_type(8)));
typedef unsigned short ushortx4 __attribute__((ext_vector_type(4)));

__device__ inline unsigned short f2b1(float f) {
  unsigned u = __float_as_uint(f);
  u += 0x7fffu + ((u >> 16) & 1u);   // RNE; inputs are finite
  return (unsigned short)(u >> 16);
}

__device__ inline void gload16(const void* g, void* l) {
  __builtin_amdgcn_global_load_lds((const __attribute__((address_space(1))) void*)g,
                                   (__attribute__((address_space(3))) void*)l, 16, 0, 0);
}

__device__ inline bf16x8 mk8(unsigned a, unsigned b, unsigned c, unsigned d) {
  uint4 t = {a, b, c, d};
  return *(bf16x8*)&t;
}

// ---------------- fused prep: x->bf16, 4 weights->bf16, bias concat ----------------
__global__ void prep(const float* __restrict__ x,
                     const float* __restrict__ w0, const float* __restrict__ w1,
                     const float* __restrict__ w2, const float* __restrict__ w3,
                     const float* __restrict__ bq, const float* __restrict__ bk,
                     const float* __restrict__ bv,
                     unsigned short* __restrict__ xb, unsigned short* __restrict__ Wqkv,
                     float* __restrict__ bqkv) {
  int bid = blockIdx.x, tid = threadIdx.x;
  if (bid < 4096) {
    int i = (bid * 256 + tid) * 4;
    float4 v = *(const float4*)(x + i);
    ushortx4 o;
    o.x = f2b1(v.x); o.y = f2b1(v.y); o.z = f2b1(v.z); o.w = f2b1(v.w);
    *(ushortx4*)(xb + i) = o;
  } else if (bid < 8192) {
    int which = (bid - 4096) >> 10;
    int i = (((bid - 4096) & 1023) * 256 + tid) * 4;
    const float* src = which == 0 ? w0 : which == 1 ? w1 : which == 2 ? w2 : w3;
    float4 v = *(const float4*)(src + i);
    ushortx4 o;
    o.x = f2b1(v.x); o.y = f2b1(v.y); o.z = f2b1(v.z); o.w = f2b1(v.w);
    *(ushortx4*)(Wqkv + (long)which * 1048576 + i) = o;
  } else {
    int i = (bid - 8192) * 256 + tid;
    if (i < 3072) {
      float v = (i < 1024) ? bq[i] : (i < 2048 ? bk[i - 1024] : bv[i - 2048]);
      bqkv[i] = v;
    }
  }
}

// ---------------- QKV GEMM: 128x128 tile, one pass (3 blocks/CU) ----------------
// Cols < 1024 scaled by scl (Q softmax fold); V cols written transposed to Vt.
__global__ __launch_bounds__(256, 3)
void gemm_qkv(const unsigned short* __restrict__ A, const unsigned short* __restrict__ B,
              const float* __restrict__ bias, unsigned short* __restrict__ Cb,
              unsigned short* __restrict__ Vt, int M, int N, int K, float scl) {
  __shared__ unsigned short As[2][4096];
  __shared__ unsigned short Bs[2][4096];
  const int tid = threadIdx.x;
  const int w = tid >> 6, lane = tid & 63;
  const int quad = lane >> 4, l16 = lane & 15;
  const int bm = blockIdx.y, bn = blockIdx.x;
  const int wm = w >> 1, wn = w & 1;

  f32x4 acc[4][4] = {};

  const int srow = tid >> 2;
  const int c4 = tid & 3;
  const unsigned short* aG = A + (long)(bm * 128 + srow) * K + c4 * 8;
  const unsigned short* bG = B + (long)(bn * 128 + srow) * K + c4 * 8;
  const long rs64 = (long)64 * K;
  const int wo = w * 512;

  gload16(aG, As[0] + wo);
  gload16(aG + rs64, As[0] + 2048 + wo);
  gload16(bG, Bs[0] + wo);
  gload16(bG + rs64, Bs[0] + 2048 + wo);

  int buf = 0;
  for (int kt = 0; kt < K; kt += 32) {
    __syncthreads();
    {
      const int nb = buf ^ 1;
      gload16(aG + kt + 32, As[nb] + wo);
      gload16(aG + rs64 + kt + 32, As[nb] + 2048 + wo);
      gload16(bG + kt + 32, Bs[nb] + wo);
      gload16(bG + rs64 + kt + 32, Bs[nb] + 2048 + wo);
    }

    bf16x8 af[4], bfr[4];
#pragma unroll
    for (int mt = 0; mt < 4; mt++)
      af[mt] = *(const bf16x8*)(As[buf] + (wm * 64 + mt * 16 + l16) * 32 + quad * 8);
#pragma unroll
    for (int nt = 0; nt < 4; nt++)
      bfr[nt] = *(const bf16x8*)(Bs[buf] + (wn * 64 + nt * 16 + l16) * 32 + quad * 8);
#pragma unroll
    for (int mt = 0; mt < 4; mt++)
#pragma unroll
      for (int nt = 0; nt < 4; nt++)
        acc[mt][nt] = __builtin_amdgcn_mfma_f32_16x16x32_bf16(af[mt], bfr[nt], acc[mt][nt], 0, 0, 0);
    buf ^= 1;
  }

  const int col0 = bn * 128 + wn * 64 + l16;
  const bool isV = (bn * 128) >= 2048;  // block-uniform
#pragma unroll
  for (int mt = 0; mt < 4; mt++) {
    int row0 = bm * 128 + wm * 64 + mt * 16 + quad * 4;
#pragma unroll
    for (int nt = 0; nt < 4; nt++) {
      int col = col0 + nt * 16;
      float bb = bias[col];
      float s = (col < 1024) ? scl : 1.0f;
      if (!isV) {
#pragma unroll
        for (int r = 0; r < 4; r++)
          Cb[(long)(row0 + r) * N + col] = f2b1((acc[mt][nt][r] + bb) * s);
      } else {
        int cv = col - 2048;
        int h = cv >> 6, d = cv & 63;
        int b = row0 >> 11, t0 = row0 & 2047;
        ushortx4 o;
        o.x = f2b1(acc[mt][nt][0] + bb);
        o.y = f2b1(acc[mt][nt][1] + bb);
        o.z = f2b1(acc[mt][nt][2] + bb);
        o.w = f2b1(acc[mt][nt][3] + bb);
        *(ushortx4*)(Vt + ((long)((b * NH + h) * DK + d)) * T_SEQ + t0) = o;
      }
    }
  }
}

// ---------------- O-proj GEMM: 64x128 tile (512 blocks, one pass) ----------------
__global__ __launch_bounds__(256, 2)
void gemm_out(const unsigned short* __restrict__ A, const unsigned short* __restrict__ B,
              const float* __restrict__ bias, float* __restrict__ Cf, int M, int N, int K) {
  __shared__ unsigned short As[2][2048];  // [64][32]
  __shared__ unsigned short Bs[2][4096];  // [128][32]
  const int tid = threadIdx.x;
  const int w = tid >> 6, lane = tid & 63;
  const int quad = lane >> 4, l16 = lane & 15;
  const int bm = blockIdx.y, bn = blockIdx.x;
  const int wm = w >> 1, wn = w & 1;

  f32x4 acc[2][4] = {};

  const int srow = tid >> 2;
  const int c4 = tid & 3;
  const unsigned short* aG = A + (long)(bm * 64 + srow) * K + c4 * 8;
  const unsigned short* bG = B + (long)(bn * 128 + srow) * K + c4 * 8;
  const long rs64 = (long)64 * K;
  const int wo = w * 512;

  gload16(aG, As[0] + wo);
  gload16(bG, Bs[0] + wo);
  gload16(bG + rs64, Bs[0] + 2048 + wo);

  int buf = 0;
  for (int kt = 0; kt < K; kt += 32) {
    __syncthreads();
    {
      const int nb = buf ^ 1;
      gload16(aG + kt + 32, As[nb] + wo);
      gload16(bG + kt + 32, Bs[nb] + wo);
      gload16(bG + rs64 + kt + 32, Bs[nb] + 2048 + wo);
    }

    bf16x8 af[2], bfr[4];
#pragma unroll
    for (int mt = 0; mt < 2; mt++)
      af[mt] = *(const bf16x8*)(As[buf] + (wm * 32 + mt * 16 + l16) * 32 + quad * 8);
#pragma unroll
    for (int nt = 0; nt < 4; nt++)
      bfr[nt] = *(const bf16x8*)(Bs[buf] + (wn * 64 + nt * 16 + l16) * 32 + quad * 8);
#pragma unroll
    for (int mt = 0; mt < 2; mt++)
#pragma unroll
      for (int nt = 0; nt < 4; nt++)
        acc[mt][nt] = __builtin_amdgcn_mfma_f32_16x16x32_bf16(af[mt], bfr[nt], acc[mt][nt], 0, 0, 0);
    buf ^= 1;
  }

  const int col0 = bn * 128 + wn * 64 + l16;
#pragma unroll
  for (int mt = 0; mt < 2; mt++) {
    int row0 = bm * 64 + wm * 32 + mt * 16 + quad * 4;
#pragma unroll
    for (int nt = 0; nt < 4; nt++) {
      int col = col0 + nt * 16;
      float bb = bias[col];
#pragma unroll
      for (int r = 0; r < 4; r++)
        Cf[(long)(row0 + r) * N + col] = acc[mt][nt][r] + bb;
    }
  }
}

// ---------------- flash attention v4: 16 rows/wave, 8 blocks/CU ----------------
// Transposed-S register-P structure (attn3) at DOUBLE occupancy: 64 Q-rows per
// 256-thread block, split-K=2 -> grid 2048 = 8 blocks/CU = 8 waves/SIMD.
// Single-buffered K/V LDS (16 KB): R5 showed dbuf is neutral; TLP covers
// latency instead. Block id low bits pin each (bh,split) to one XCD (2MB KV).
__global__ __launch_bounds__(256, 8)
void attn4(const unsigned short* __restrict__ QKV, const unsigned short* __restrict__ Vt,
           unsigned short* __restrict__ Onum, float* __restrict__ Oden) {
  __shared__ unsigned short Ks[4096];   // [64 key][64 d], chunk ^= (key&7)
  __shared__ unsigned short Vs[4096];   // [64 d][64 key], chunk ^= (d&7)
  const int tid = threadIdx.x;
  const int w = tid >> 6, lane = tid & 63;
  const int quad = lane >> 4, l16 = lane & 15;

  const int id = blockIdx.x;
  const int g64 = id & 63;        // (bh,split): id%8 fixed -> same XCD for group
  const int qt = id >> 6;         // 0..31 (64-row Q tiles)
  const int bh = g64 >> 1, split = g64 & 1;
  const int b = bh >> 4, h = bh & 15;
  const long qkvBase = (long)b * T_SEQ * 3072;
  const int kv0 = split * 1024;

  // Q fragment (B-operand): lane's own Q-row = l16 of this wave's 16
  const unsigned short* qp = QKV + qkvBase + (long)(qt * 64 + w * 16 + l16) * 3072 + h * 64 + quad * 8;
  bf16x8 qf0 = *(const bf16x8*)qp;
  bf16x8 qf1 = *(const bf16x8*)(qp + 32);

  const unsigned short* kG[2];
  const unsigned short* vG[2];
#pragma unroll
  for (int i = 0; i < 2; i++) {
    int S = w * 128 + i * 64 + lane;
    int row = S >> 3;
    int c = (S & 7) ^ (row & 7);
    kG[i] = QKV + qkvBase + 1024 + h * 64 + (long)(kv0 + row) * 3072 + c * 8;
    vG[i] = Vt + (long)bh * DK * T_SEQ + (long)row * T_SEQ + kv0 + c * 8;
  }
  const int wo2 = w * 1024;

  f32x4 acco[4] = {};
  float psum = 0.f;
  const int e16 = (l16 & 7) * 16;

  for (int it = 0; it < 16; it++) {
    __syncthreads();   // previous tile's LDS reads done before overwrite
    gload16(kG[0], Ks + wo2);
    gload16(kG[1], Ks + wo2 + 512);
    gload16(vG[0], Vs + wo2);
    gload16(vG[1], Vs + wo2 + 512);
    kG[0] += 64 * 3072; kG[1] += 64 * 3072;
    vG[0] += 64;        vG[1] += 64;
    __syncthreads();   // staged

    // ---- S^T = K Q^T : lane gets its own Q-row (l16), keys nt*16+quad*4+r ----
    f32x4 st[4];
#pragma unroll
    for (int nt = 0; nt < 4; nt++) {
      const char* kr = (char*)Ks + (nt * 16 + l16) * 128;
      bf16x8 k0 = *(const bf16x8*)(kr + ((quad * 16) ^ e16));
      bf16x8 k1 = *(const bf16x8*)(kr + (((quad + 4) * 16) ^ e16));
      f32x4 z = {};
      z = __builtin_amdgcn_mfma_f32_16x16x32_bf16(k0, qf0, z, 0, 0, 0);
      z = __builtin_amdgcn_mfma_f32_16x16x32_bf16(k1, qf1, z, 0, 0, 0);
      st[nt] = z;
    }

    // ---- p = exp2(s), pack in-register into PV A-fragments ----
    unsigned pk[4][2];
#pragma unroll
    for (int nt = 0; nt < 4; nt++) {
      float p0 = __builtin_amdgcn_exp2f(st[nt][0]);
      float p1 = __builtin_amdgcn_exp2f(st[nt][1]);
      float p2 = __builtin_amdgcn_exp2f(st[nt][2]);
      float p3 = __builtin_amdgcn_exp2f(st[nt][3]);
      psum += (p0 + p1) + (p2 + p3);
      unsigned a0 = __float_as_uint(p0) + 0x8000u;
      unsigned a1 = __float_as_uint(p1) + 0x8000u;
      unsigned a2 = __float_as_uint(p2) + 0x8000u;
      unsigned a3 = __float_as_uint(p3) + 0x8000u;
      pk[nt][0] = __builtin_amdgcn_perm(a1, a0, 0x07060302u);
      pk[nt][1] = __builtin_amdgcn_perm(a3, a2, 0x07060302u);
    }
    bf16x8 pa0 = mk8(pk[0][0], pk[0][1], pk[1][0], pk[1][1]);  // keys 0..31 (kappa)
    bf16x8 pa1 = mk8(pk[2][0], pk[2][1], pk[3][0], pk[3][1]);  // keys 32..63

    // ---- O += P V ----
    const int off8 = (quad & 1) * 8;
    const int cq = quad >> 1;
#pragma unroll
    for (int nt = 0; nt < 4; nt++) {
      const char* vr = (char*)Vs + (nt * 16 + l16) * 128;
#pragma unroll
      for (int km = 0; km < 2; km++) {
        uint2 lo = *(const uint2*)(vr + (((km * 4 + cq) * 16) ^ e16) + off8);
        uint2 hi = *(const uint2*)(vr + (((km * 4 + cq + 2) * 16) ^ e16) + off8);
        bf16x8 vf = mk8(lo.x, lo.y, hi.x, hi.y);
        acco[nt] = __builtin_amdgcn_mfma_f32_16x16x32_bf16(km == 0 ? pa0 : pa1, vf, acco[nt], 0, 0, 0);
      }
    }
  }

  // ---- psum over quads -> per-row denominators; write bf16 numerators ----
  const long rowBase = (long)bh * T_SEQ + qt * 64 + w * 16;
  const long numBase = ((long)split * 65536 + rowBase) * 64;
  float v = psum;
  v += __shfl_xor(v, 16, 64);
  v += __shfl_xor(v, 32, 64);
  if (lane < 16)
    Oden[(long)split * 65536 + rowBase + lane] = v;
#pragma unroll
  for (int nt = 0; nt < 4; nt++)
#pragma unroll
    for (int r = 0; r < 4; r++)
      Onum[numBase + (long)(quad * 4 + r) * 64 + nt * 16 + l16] = f2b1(acco[nt][r]);
}

// ---------------- combine splits (bf16 partials) ----------------
__global__ __launch_bounds__(256)
void combine(const unsigned short* __restrict__ Onum, const float* __restrict__ Oden,
             unsigned short* __restrict__ Ob) {
  int idx = blockIdx.x * 256 + threadIdx.x;
  int rp = idx >> 4;
  int dq = (idx & 15) * 4;
  ushortx4 n0 = *(const ushortx4*)(Onum + (long)rp * 64 + dq);
  ushortx4 n1 = *(const ushortx4*)(Onum + 4194304L + (long)rp * 64 + dq);
  float den = Oden[rp] + Oden[65536 + rp];
  float rl = __builtin_amdgcn_rcpf(den);
  int bh = rp >> 11, t = rp & 2047;
  int b = bh >> 4, h = bh & 15;
  ushortx4 o;
  o.x = f2b1((__uint_as_float((unsigned)n0.x << 16) + __uint_as_float((unsigned)n1.x << 16)) * rl);
  o.y = f2b1((__uint_as_float((unsigned)n0.y << 16) + __uint_as_float((unsigned)n1.y << 16)) * rl);
  o.z = f2b1((__uint_as_float((unsigned)n0.z << 16) + __uint_as_float((unsigned)n1.z << 16)) * rl);
  o.w = f2b1((__uint_as_float((unsigned)n0.w << 16) + __uint_as_float((unsigned)n1.w << 16)) * rl);
  *(ushortx4*)(Ob + (long)(b * T_SEQ + t) * DMODEL + h * 64 + dq) = o;
}

extern "C" void kernel_launch(void* const* d_in, const int* in_sizes, int n_in,
                              void* d_out, int out_size, void* d_ws, size_t ws_size,
                              hipStream_t stream) {
  const float* x  = (const float*)d_in[0];
  const float* Wq = (const float*)d_in[1];
  const float* bq = (const float*)d_in[2];
  const float* Wk = (const float*)d_in[3];
  const float* bk = (const float*)d_in[4];
  const float* Wv = (const float*)d_in[5];
  const float* bv = (const float*)d_in[6];
  const float* Wo = (const float*)d_in[7];
  const float* bo = (const float*)d_in[8];
  float* out = (float*)d_out;

  unsigned short* xb   = (unsigned short*)d_ws;        // 4M elems
  unsigned short* Wqkv = xb + 4194304;                 // 3M
  unsigned short* Wob  = Wqkv + 3145728;               // 1M
  float*          bqkv = (float*)(Wob + 1048576);      // 3072 f32
  unsigned short* QKV  = (unsigned short*)(bqkv + 3072);  // 12.58M elems (Q,K used)
  unsigned short* Vt   = QKV + 12582912;               // 4M
  unsigned short* Ob   = Vt + 4194304;                 // 4M
  unsigned short* Onum = Ob + 4194304;                 // 8.39M ush (2 splits)
  float*          Oden = (float*)(Onum + 8388608);     // 131072 f32

  prep<<<8204, 256, 0, stream>>>(x, Wq, Wk, Wv, Wo, bq, bk, bv, xb, Wqkv, bqkv);

  // QKV = x @ [Wq|Wk|Wv]^T + b; Q pre-scaled; V written transposed into Vt
  gemm_qkv<<<dim3(24, 32), 256, 0, stream>>>(xb, Wqkv, bqkv, QKV, Vt,
                                             4096, 3072, 1024, 0.04508422037f);

  attn4<<<dim3(2048), 256, 0, stream>>>(QKV, Vt, Onum, Oden);
  combine<<<dim3(4096), 256, 0, stream>>>(Onum, Oden, Ob);

  // out = O @ Wo^T + bo : fp32 out, 64x128 tiles, 512 blocks
  gemm_out<<<dim3(8, 64), 256, 0, stream>>>(Ob, Wob, bo, out, 4096, 1024, 1024);
}